// Round 2
// baseline (21194.675 us; speedup 1.0000x reference)
//
#include <hip/hip_runtime.h>

typedef __bf16 bf16_t;
typedef bf16_t bf16x8 __attribute__((ext_vector_type(8)));
typedef float  f32x4  __attribute__((ext_vector_type(4)));

#define MFMA16(A, B, C) __builtin_amdgcn_mfma_f32_16x16x32_bf16((A), (B), (C), 0, 0, 0)

static constexpr int KEXT   = 288;   // ws weight row stride: 256 h | 3 x | 1 bias | pad
static constexpr int HS     = 296;   // LDS row stride (592 B -> 2-way bank alias, free)
static constexpr int HB_W   = 264;   // Hbuf row stride: 256 h | 3 x | 1 ones | 4 pad (528 B, 16B-aligned)
static constexpr int TSTEPS = 128;

// ws layout (bf16 elements)
static constexpr int WALL_OFF = 0;                    // [1152][288] gates(1024)+Wo1(128)
static constexpr int W2E_OFF  = 1152 * 288;           // [512][288]  encoder layer2 (+b2 col)
static constexpr int WO2E_OFF = W2E_OFF + 512 * 288;  // [16][128]   Wo2 padded
static constexpr int HBUF_OFF = WO2E_OFF + 16 * 128;  // [2][4096][264] h/x exchange
static constexpr int BAR_OFF  = HBUF_OFF + 2 * 4096 * HB_W; // 64 groups x 16 uints (as 2048 bf16)
static constexpr int PREP_N   = BAR_OFF + 4096 * 16 / 1 ;   // prep idx space: see below

static constexpr int HB_INIT0 = HBUF_OFF;  // marker only

// ---------------- prep: pack weights bf16, init Hbuf x/ones/pad cols, zero barriers ----------------
__global__ __launch_bounds__(256) void prep_kernel(
    const float* __restrict__ meta,
    const float* __restrict__ W2,  const float* __restrict__ b2,
    const float* __restrict__ Wih, const float* __restrict__ Whh,
    const float* __restrict__ bih, const float* __restrict__ bhh,
    const float* __restrict__ Wo1, const float* __restrict__ bo1,
    const float* __restrict__ Wo2, bf16_t* __restrict__ ws)
{
    int idx = blockIdx.x * 256 + threadIdx.x;
    if (idx < 1152 * 288) {
        int r = idx / 288, k = idx - r * 288;
        float v = 0.f;
        if (r < 1024) {                       // gate rows: i f g o
            if (k < 256)       v = Whh[r * 256 + k];
            else if (k < 259)  v = Wih[r * 3 + (k - 256)];
            else if (k == 259) v = bih[r] + bhh[r];
        } else {                              // Wo1 rows
            int q = r - 1024;
            if (k < 256)       v = Wo1[q * 256 + k];
            else if (k == 259) v = bo1[q];
        }
        ws[WALL_OFF + idx] = (bf16_t)v;
    } else if (idx < W2E_OFF + 512 * 288) {
        int j = idx - W2E_OFF;
        int u = j / 288, k = j - u * 288;
        float v = 0.f;
        if (k < 256)       v = W2[u * 256 + k];
        else if (k == 259) v = b2[u];
        ws[idx] = (bf16_t)v;
    } else if (idx < HBUF_OFF) {
        int j = idx - WO2E_OFF;
        int d = j >> 7, q = j & 127;
        ws[idx] = (bf16_t)((d < 3) ? Wo2[d * 128 + q] : 0.f);
    } else if (idx < HBUF_OFF + 4096 * 16) {
        // Hbuf cols 256..263 for both buffers
        int j = idx - HBUF_OFF;
        int b = j >> 4, sub = j & 15;
        int buf = sub >> 3, c = 256 + (sub & 7);
        float v = 0.f;
        if (c < 259)       v = (buf == 0) ? meta[b * 7 + (c - 256)] : 0.f; // x0 in buf0
        else if (c == 259) v = 1.f;                                        // ones col, both bufs
        ws[HBUF_OFF + ((size_t)buf * 4096 + b) * HB_W + c] = (bf16_t)v;
    } else if (idx < HBUF_OFF + 4096 * 16 + 1024) {
        // zero group-barrier counters (64 groups x 16 uints)
        int j = idx - (HBUF_OFF + 4096 * 16);
        ((unsigned*)(ws + BAR_OFF))[j] = 0u;
    }
}

__device__ __forceinline__ float sigm(float x) { return 1.f / (1.f + __expf(-x)); }
__device__ __forceinline__ float tanh_f(float x) {
    float a = fminf(fmaxf(x, -15.f), 15.f);
    float e = __expf(2.f * a);
    return (e - 1.f) / (e + 1.f);
}
__device__ __forceinline__ unsigned pk2(float a, float b) {
    union { bf16_t h[2]; unsigned u; } x;
    x.h[0] = (bf16_t)a; x.h[1] = (bf16_t)b; return x.u;
}

// device-scope group barrier (monotonic counter, 4 blocks/group)
__device__ __forceinline__ void gbar(unsigned* ctr, unsigned target) {
    __threadfence();                 // release my stores (agent scope)
    __syncthreads();
    if (threadIdx.x == 0) {
        __hip_atomic_fetch_add(ctr, 1u, __ATOMIC_RELEASE, __HIP_MEMORY_SCOPE_AGENT);
        while (__hip_atomic_load(ctr, __ATOMIC_RELAXED, __HIP_MEMORY_SCOPE_AGENT) < target)
            __builtin_amdgcn_s_sleep(1);
    }
    __syncthreads();
    __threadfence();                 // acquire: invalidate stale cache lines
}

// ---------------- main: 256 blocks (1/CU), 4-block groups share a 64-batch tile ----------------
// block j of group g: gate dims [64j,64j+64), Wo1 full in LDS, batch slice [16j,16j+16) for y.
// Weights for gates held PERMANENTLY in VGPRs (af[4][9] bf16x8 = 144 VGPRs/lane).
__global__ __launch_bounds__(512, 2) void lstm_main(
    const float* __restrict__ meta, const float* __restrict__ W1,
    const float* __restrict__ b1,   const float* __restrict__ bo2,
    bf16_t* __restrict__ ws,        float* __restrict__ out)
{
    __shared__ __align__(16) bf16_t hext[64][HS];   // [h|x|1|0pad] for group's 64 batches
    __shared__ __align__(16) bf16_t zhin[16][HS];   // h_{t+1} for my 16 batches
    __shared__ __align__(16) bf16_t wo1l[128][HS];  // Wo1 (aliased as cbuf fp32[64][66] in setup)
    __shared__ __align__(16) bf16_t wo2l[16][136];
    __shared__ __align__(16) bf16_t zbuf[16][136];  // z: [batch][zdim]

    const int tid  = threadIdx.x;
    const int wv   = tid >> 6;
    const int lane = tid & 63;
    const int l15  = lane & 15;
    const int quad = lane >> 4;
    const int g    = blockIdx.x & 63;    // group: members {g, g+64, g+128, g+192} (same XCD under %8 rr)
    const int j    = blockIdx.x >> 6;    // member 0..3
    const int gb   = g * 64;             // group batch base
    const int q    = wv >> 1;            // dim chunk 0..3 (16 dims)
    const int nh   = wv & 1;             // batch half 0..1 (32 batches)
    const int d0   = 64 * j + 16 * q;    // global dim base of this wave's chunk

    bf16_t* wall = ws + WALL_OFF;
    bf16_t* w2e  = ws + W2E_OFF;
    bf16_t* wo2e = ws + WO2E_OFF;
    bf16_t* hbuf = ws + HBUF_OFF;
    unsigned* ctr = (unsigned*)(ws + BAR_OFF) + (size_t)g * 16;

    const f32x4 zero4 = {0.f, 0.f, 0.f, 0.f};

    // ---- setup: enc1 (VALU, K=7) into hext; ext cols; wo2l copy ----
    {
        int b  = tid & 63;
        int jb = (tid >> 6) * 32;
        float m[7];
        #pragma unroll
        for (int k = 0; k < 7; ++k) m[k] = meta[(size_t)(gb + b) * 7 + k];
        #pragma unroll
        for (int jj = 0; jj < 32; ++jj) {
            int jd = jb + jj;
            float acc = b1[jd];
            #pragma unroll
            for (int k = 0; k < 7; ++k) acc += W1[jd * 7 + k] * m[k];
            hext[b][jd] = (bf16_t)fmaxf(acc, 0.f);
        }
        if (tid < 64)
            for (int c = 256; c < HS; ++c) hext[tid][c] = (bf16_t)((c == 259) ? 1.f : 0.f);
        for (int i = 0; i < 4; ++i) {                       // wo2l
            int idx = tid + 512 * i;
            int r = idx >> 7, c = idx & 127;
            wo2l[r][c] = wo2e[r * 128 + c];
        }
        if (tid < 64) {                                     // zhin pad cols 264..295 = 0
            int r = tid >> 2, c8 = 33 + (tid & 3);
            *(bf16x8*)&zhin[r][8 * c8] = bf16x8{};
        }
    }
    __syncthreads();

    // ---- enc2 via MFMA: wave w -> u=w&3 (16 dims), hc=w>>2 (0:h0, 1:c0), all 64 batches ----
    float* cbuf = (float*)&wo1l[0][0];  // [64][66] fp32, local dims x batches
    {
        const int u = wv & 3, hc = wv >> 2;
        const int arow = hc * 256 + 64 * j + 16 * u + l15;
        f32x4 eacc[4] = {zero4, zero4, zero4, zero4};
        for (int kk = 0; kk < 9; ++kk) {
            int ko = 32 * kk + 8 * quad;
            bf16x8 af = *(const bf16x8*)&w2e[(size_t)arow * KEXT + ko];
            #pragma unroll
            for (int nt = 0; nt < 4; ++nt) {
                bf16x8 bf = *(const bf16x8*)&hext[16 * nt + l15][ko];
                eacc[nt] = MFMA16(af, bf, eacc[nt]);
            }
        }
        bf16_t* h0dst = hbuf;  // buffer 0
        #pragma unroll
        for (int nt = 0; nt < 4; ++nt) {
            int batch = gb + 16 * nt + l15;
            if (hc == 0) {
                int dim = 64 * j + 16 * u + 4 * quad;
                unsigned p0 = pk2(fmaxf(eacc[nt][0], 0.f), fmaxf(eacc[nt][1], 0.f));
                unsigned p1 = pk2(fmaxf(eacc[nt][2], 0.f), fmaxf(eacc[nt][3], 0.f));
                *(unsigned*)&h0dst[(size_t)batch * HB_W + dim]     = p0;
                *(unsigned*)&h0dst[(size_t)batch * HB_W + dim + 2] = p1;
            } else {
                #pragma unroll
                for (int r = 0; r < 4; ++r)
                    cbuf[(16 * u + 4 * quad + r) * 66 + 16 * nt + (lane & 15)] = fmaxf(eacc[nt][r], 0.f);
            }
        }
    }
    __syncthreads();

    // ---- read c0 into loop layout: dims d0+4quad+r, batches 32nh+16nt+l15 ----
    float c[2][4];
    #pragma unroll
    for (int nt = 0; nt < 2; ++nt)
        #pragma unroll
        for (int r = 0; r < 4; ++r)
            c[nt][r] = cbuf[(16 * q + 4 * quad + r) * 66 + 32 * nh + 16 * nt + l15];
    __syncthreads();

    // ---- load Wo1 into LDS (overwrites cbuf) ----
    for (int i = 0; i < 9; ++i) {
        int idx = tid + 512 * i;
        if (idx < 128 * 36) {
            int r = idx / 36, c8 = idx - r * 36;
            *(bf16x8*)&wo1l[r][8 * c8] = *(const bf16x8*)&wall[(size_t)(1024 + r) * KEXT + 8 * c8];
        }
    }

    // ---- preload gate A-fragments into registers: af[gate][kk] ----
    bf16x8 af[4][9];
    #pragma unroll
    for (int m = 0; m < 4; ++m)
        #pragma unroll
        for (int kk = 0; kk < 9; ++kk)
            af[m][kk] = *(const bf16x8*)&wall[(size_t)(256 * m + d0 + l15) * KEXT + 32 * kk + 8 * quad];

    unsigned bar = 1;
    gbar(ctr, 4 * bar);   // h0 (+x0 from prep) published

    // ================= time loop =================
    for (int t = 0; t < TSTEPS; ++t) {
        const bf16_t* hsrc = hbuf + (size_t)(t & 1) * 4096 * HB_W;
        bf16_t*       hdst = hbuf + (size_t)((t + 1) & 1) * 4096 * HB_W;

        // -- stage [h_t|x_t|1] for group's 64 batches: 64 rows x 33 16B-chunks --
        #pragma unroll
        for (int i = 0; i < 5; ++i) {
            int idx = tid + 512 * i;
            if (idx < 64 * 33) {
                int row = idx / 33, c8 = idx - row * 33;
                *(bf16x8*)&hext[row][8 * c8] =
                    *(const bf16x8*)&hsrc[(size_t)(gb + row) * HB_W + 8 * c8];
            }
        }
        __syncthreads();

        // -- gates: A in regs, B from LDS; acc[gate][nt] --
        f32x4 acc[4][2];
        #pragma unroll
        for (int m = 0; m < 4; ++m) { acc[m][0] = zero4; acc[m][1] = zero4; }
        #pragma unroll
        for (int kk = 0; kk < 9; ++kk) {
            int ko = 32 * kk + 8 * quad;
            bf16x8 bf0 = *(const bf16x8*)&hext[32 * nh + l15][ko];
            bf16x8 bf1 = *(const bf16x8*)&hext[32 * nh + 16 + l15][ko];
            #pragma unroll
            for (int m = 0; m < 4; ++m) {
                acc[m][0] = MFMA16(af[m][kk], bf0, acc[m][0]);
                acc[m][1] = MFMA16(af[m][kk], bf1, acc[m][1]);
            }
        }

        // -- cell update (all in regs) + publish h_{t+1} slice --
        #pragma unroll
        for (int nt = 0; nt < 2; ++nt) {
            float hh[4];
            #pragma unroll
            for (int r = 0; r < 4; ++r) {
                float iv = acc[0][nt][r], fv = acc[1][nt][r];
                float gv = acc[2][nt][r], ov = acc[3][nt][r];
                float cc = sigm(fv) * c[nt][r] + sigm(iv) * tanh_f(gv);
                c[nt][r] = cc;
                hh[r] = sigm(ov) * tanh_f(cc);
            }
            int batch = gb + 32 * nh + 16 * nt + l15;
            int dim   = d0 + 4 * quad;
            *(unsigned*)&hdst[(size_t)batch * HB_W + dim]     = pk2(hh[0], hh[1]);
            *(unsigned*)&hdst[(size_t)batch * HB_W + dim + 2] = pk2(hh[2], hh[3]);
        }

        gbar(ctr, 4 * (++bar));   // S1: full h_{t+1} visible

        // -- window B: z = relu(h_{t+1} @ Wo1^T) for my 16 batches --
        #pragma unroll
        for (int i = 0; i < 2; ++i) {
            int idx = tid + 512 * i;
            if (idx < 16 * 33) {
                int row = idx / 33, c8 = idx - row * 33;
                *(bf16x8*)&zhin[row][8 * c8] =
                    *(const bf16x8*)&hdst[(size_t)(gb + 16 * j + row) * HB_W + 8 * c8];
            }
        }
        __syncthreads();

        f32x4 zacc = zero4;
        #pragma unroll
        for (int kk = 0; kk < 9; ++kk) {
            int ko = 32 * kk + 8 * quad;
            bf16x8 a = *(const bf16x8*)&wo1l[16 * wv + l15][ko];
            bf16x8 b = *(const bf16x8*)&zhin[l15][ko];
            zacc = MFMA16(a, b, zacc);
        }
        {
            int zd = 16 * wv + 4 * quad;
            *(unsigned*)&zbuf[l15][zd]     = pk2(fmaxf(zacc[0], 0.f), fmaxf(zacc[1], 0.f));
            *(unsigned*)&zbuf[l15][zd + 2] = pk2(fmaxf(zacc[2], 0.f), fmaxf(zacc[3], 0.f));
        }
        __syncthreads();

        // -- y = z @ Wo2^T + bo2 (wave 0); emit out + x_{t+1} --
        if (wv == 0) {
            f32x4 ya = zero4;
            #pragma unroll
            for (int kk = 0; kk < 4; ++kk) {
                int ko = 32 * kk + 8 * quad;
                ya = MFMA16(*(const bf16x8*)&wo2l[l15][ko],
                            *(const bf16x8*)&zbuf[l15][ko], ya);
            }
            if (quad == 0) {
                int batch = gb + 16 * j + l15;
                float y0 = ya[0] + bo2[0], y1 = ya[1] + bo2[1], y2 = ya[2] + bo2[2];
                float* op = out + (size_t)batch * (TSTEPS * 3) + t * 3;
                op[0] = y0; op[1] = y1; op[2] = y2;
                *(unsigned*)&hdst[(size_t)batch * HB_W + 256] = pk2(y0, y1);
                *(unsigned*)&hdst[(size_t)batch * HB_W + 258] = pk2(y2, 1.f);
            }
        }

        gbar(ctr, 4 * (++bar));   // S2: x_{t+1} visible
    }
}

extern "C" void kernel_launch(void* const* d_in, const int* in_sizes, int n_in,
                              void* d_out, int out_size, void* d_ws, size_t ws_size,
                              hipStream_t stream)
{
    const float* meta = (const float*)d_in[0];
    const float* W1   = (const float*)d_in[2];
    const float* b1   = (const float*)d_in[3];
    const float* W2   = (const float*)d_in[4];
    const float* b2   = (const float*)d_in[5];
    const float* Wih  = (const float*)d_in[6];
    const float* Whh  = (const float*)d_in[7];
    const float* bih  = (const float*)d_in[8];
    const float* bhh  = (const float*)d_in[9];
    const float* Wo1  = (const float*)d_in[10];
    const float* bo1  = (const float*)d_in[11];
    const float* Wo2  = (const float*)d_in[12];
    const float* bo2  = (const float*)d_in[13];
    bf16_t* ws  = (bf16_t*)d_ws;
    float*  out = (float*)d_out;

    int prep_n = HBUF_OFF + 4096 * 16 + 1024;
    prep_kernel<<<dim3((prep_n + 255) / 256), dim3(256), 0, stream>>>(
        meta, W2, b2, Wih, Whh, bih, bhh, Wo1, bo1, Wo2, ws);
    lstm_main<<<dim3(256), dim3(512), 0, stream>>>(meta, W1, b1, bo2, ws, out);
}

// Round 3
// 1491.695 us; speedup vs baseline: 14.2084x; 14.2084x over previous
//
#include <hip/hip_runtime.h>

typedef __bf16 bf16_t;
typedef bf16_t bf16x8 __attribute__((ext_vector_type(8)));
typedef float  f32x4  __attribute__((ext_vector_type(4)));

#define MFMA16(A, B, C) __builtin_amdgcn_mfma_f32_16x16x32_bf16((A), (B), (C), 0, 0, 0)

static constexpr int KEXT   = 288;  // 256 h | 3 x | 1 ones(bias) | 28 zero pad
static constexpr int HS     = 296;  // LDS row stride (592 B = 37*16: aligned, 2-way bank alias only)
static constexpr int TSTEPS = 128;
static constexpr int TILE_B = 16;   // grid 256 -> 1 block/CU, all CUs busy

// ws layout (bf16 elements)
static constexpr int WALL_OFF = 0;                    // [1152][288] gates(1024) + Wo1ext(128)
static constexpr int W2E_OFF  = 1152 * 288;           // [512][288]  encoder layer2 (+b2 col)
static constexpr int WO2E_OFF = W2E_OFF + 512 * 288;  // [16][128]   Wo2 padded
static constexpr int WS_ELEMS = WO2E_OFF + 16 * 128;

// ---------------- prep: pack weights bf16 (ws re-poisoned every launch) ----------------
__global__ __launch_bounds__(256) void prep_kernel(
    const float* __restrict__ W2,  const float* __restrict__ b2,
    const float* __restrict__ Wih, const float* __restrict__ Whh,
    const float* __restrict__ bih, const float* __restrict__ bhh,
    const float* __restrict__ Wo1, const float* __restrict__ bo1,
    const float* __restrict__ Wo2, bf16_t* __restrict__ ws)
{
    int idx = blockIdx.x * 256 + threadIdx.x;
    if (idx < 1152 * 288) {
        int r = idx / 288, k = idx - r * 288;
        float v = 0.f;
        if (r < 1024) {                       // gate rows: i f g o (256 each)
            if (k < 256)       v = Whh[r * 256 + k];
            else if (k < 259)  v = Wih[r * 3 + (k - 256)];
            else if (k == 259) v = bih[r] + bhh[r];
        } else {                              // Wo1 rows (zeros at x cols, bo1 at ones col)
            int q = r - 1024;
            if (k < 256)       v = Wo1[q * 256 + k];
            else if (k == 259) v = bo1[q];
        }
        ws[WALL_OFF + idx] = (bf16_t)v;
    } else if (idx < W2E_OFF + 512 * 288) {
        int j = idx - W2E_OFF;
        int u = j / 288, k = j - u * 288;
        float v = 0.f;
        if (k < 256)       v = W2[u * 256 + k];
        else if (k == 259) v = b2[u];
        ws[idx] = (bf16_t)v;
    } else if (idx < WS_ELEMS) {
        int j = idx - WO2E_OFF;
        int d = j >> 7, q = j & 127;
        ws[idx] = (bf16_t)((d < 3) ? Wo2[d * 128 + q] : 0.f);
    }
}

__device__ __forceinline__ float sigm(float x) { return 1.f / (1.f + __expf(-x)); }
__device__ __forceinline__ float tanh_f(float x) {
    float a = fminf(fmaxf(x, -15.f), 15.f);
    float e = __expf(2.f * a);
    return (e - 1.f) / (e + 1.f);
}
__device__ __forceinline__ unsigned pk2(float a, float b) {
    union { bf16_t h[2]; unsigned u; } x;
    x.h[0] = (bf16_t)a; x.h[1] = (bf16_t)b; return x.u;
}

// ---------------- main: 256 blocks x 512 thr; block owns 16 batches end-to-end.
// Wave wv: dims [32wv,32wv+16) x 4 gates register-resident (af, 144 VGPR);
// dims [32wv+16,32wv+32) x 4 gates streamed from L2 (295 KB/step/CU).
// Wo1/Wo2 LDS-resident. Block-local only: 3 s_barrier per step, no fences.
__global__ __launch_bounds__(512, 2) void lstm_main(
    const float* __restrict__ meta, const float* __restrict__ W1,
    const float* __restrict__ b1,   const float* __restrict__ bo2,
    const bf16_t* __restrict__ ws,  float* __restrict__ out)
{
    __shared__ __align__(16) bf16_t hx[2][TILE_B][HS];  // [h(256)|x(3)|1|pad] double-buffered
    __shared__ __align__(16) bf16_t wo1l[128][HS];      // Wo1ext; aliased as cbuf fp32 in setup
    __shared__ __align__(16) bf16_t wo2l[16][136];
    __shared__ __align__(16) bf16_t zbuf[TILE_B][136];

    const int tid  = threadIdx.x;
    const int wv   = tid >> 6;       // 0..7
    const int lane = tid & 63;
    const int l15  = lane & 15;
    const int quad = lane >> 4;      // 0..3
    const int gb   = blockIdx.x * TILE_B;

    const bf16_t* wall = ws + WALL_OFF;
    const bf16_t* w2e  = ws + W2E_OFF;
    const bf16_t* wo2e = ws + WO2E_OFF;

    const int rd0 = 32 * wv;         // register-resident dim base
    const int sd0 = 32 * wv + 16;    // streamed dim base
    const f32x4 zero4 = {0.f, 0.f, 0.f, 0.f};

    // ---- init ext cols of both hx buffers (x0 in buf0; ones col; zero pad) ----
    if (tid < 32) {
        int buf = tid >> 4, b = tid & 15;
        for (int c = 256; c < HS; ++c) {
            float v = 0.f;
            if (c < 259)       v = buf ? 0.f : meta[(size_t)(gb + b) * 7 + (c - 256)];
            else if (c == 259) v = 1.f;
            hx[buf][b][c] = (bf16_t)v;
        }
    }
    // ---- enc1 (VALU, K=7) into hx[1]: thread -> batch tid&15, dims 8*(tid>>4) ----
    {
        int b = tid & 15, j0 = (tid >> 4) * 8;
        float m[7];
        #pragma unroll
        for (int k = 0; k < 7; ++k) m[k] = meta[(size_t)(gb + b) * 7 + k];
        #pragma unroll
        for (int jj = 0; jj < 8; ++jj) {
            int jd = j0 + jj;
            float acc = b1[jd];
            #pragma unroll
            for (int k = 0; k < 7; ++k) acc += W1[jd * 7 + k] * m[k];
            hx[1][b][jd] = (bf16_t)fmaxf(acc, 0.f);
        }
    }
    __syncthreads();

    // ---- enc2 via MFMA: wave wv owns rows [64wv,64wv+64); rows<256 -> h0(hx[0]), >=256 -> c0(cbuf) ----
    float* cbuf = (float*)&wo1l[0][0];  // fp32 [256][17]
    {
        f32x4 e[4] = {zero4, zero4, zero4, zero4};
        #pragma unroll
        for (int kk = 0; kk < 9; ++kk) {
            int ko = 32 * kk + 8 * quad;
            bf16x8 bf = *(const bf16x8*)&hx[1][l15][ko];
            #pragma unroll
            for (int m = 0; m < 4; ++m) {
                bf16x8 a = *(const bf16x8*)&w2e[(size_t)(64 * wv + 16 * m + l15) * KEXT + ko];
                e[m] = MFMA16(a, bf, e[m]);
            }
        }
        #pragma unroll
        for (int m = 0; m < 4; ++m) {
            int row = 64 * wv + 16 * m + 4 * quad;
            if (row < 256) {  // h0
                *(unsigned*)&hx[0][l15][row]     = pk2(fmaxf(e[m][0], 0.f), fmaxf(e[m][1], 0.f));
                *(unsigned*)&hx[0][l15][row + 2] = pk2(fmaxf(e[m][2], 0.f), fmaxf(e[m][3], 0.f));
            } else {          // c0
                int d = row - 256;
                #pragma unroll
                for (int r = 0; r < 4; ++r)
                    cbuf[(size_t)(d + r) * 17 + l15] = fmaxf(e[m][r], 0.f);
            }
        }
    }
    __syncthreads();

    // ---- c0 -> regs in loop layout: c[half][r] at dim (rd0|sd0)+4quad+r, batch l15 ----
    f32x4 c[2];
    #pragma unroll
    for (int half = 0; half < 2; ++half)
        #pragma unroll
        for (int r = 0; r < 4; ++r)
            c[half][r] = cbuf[(size_t)(32 * wv + 16 * half + 4 * quad + r) * 17 + l15];
    __syncthreads();

    // ---- load Wo1 into LDS (overwrites cbuf); Wo2 into LDS; af into VGPRs ----
    #pragma unroll
    for (int i = 0; i < 9; ++i) {
        int idx = tid + 512 * i;
        int r = idx / 36, c8 = idx - r * 36;
        *(bf16x8*)&wo1l[r][8 * c8] = *(const bf16x8*)&wall[(size_t)(1024 + r) * KEXT + 8 * c8];
    }
    #pragma unroll
    for (int i = 0; i < 4; ++i) {
        int idx = tid + 512 * i;
        int r = idx >> 7, cc = idx & 127;
        wo2l[r][cc] = wo2e[r * 128 + cc];
    }
    bf16x8 af[4][9];
    #pragma unroll
    for (int g = 0; g < 4; ++g)
        #pragma unroll
        for (int kk = 0; kk < 9; ++kk)
            af[g][kk] = *(const bf16x8*)&wall[(size_t)(256 * g + rd0 + l15) * KEXT + 32 * kk + 8 * quad];

    const bf16_t* sbase[4];
    #pragma unroll
    for (int g = 0; g < 4; ++g)
        sbase[g] = wall + (size_t)(256 * g + sd0 + l15) * KEXT + 8 * quad;

    __syncthreads();

    // ================= time loop =================
    for (int t = 0; t < TSTEPS; ++t) {
        const bf16_t (*cur)[HS] = hx[t & 1];
        bf16_t (*nxt)[HS]       = hx[(t + 1) & 1];

        // -- phase 1: gates = [h|x|1] @ Wall^T; A: regs (low half) + L2 stream (high half) --
        f32x4 aR[4] = {zero4, zero4, zero4, zero4};
        f32x4 aS[4] = {zero4, zero4, zero4, zero4};
        #pragma unroll
        for (int kk = 0; kk < 9; ++kk) {
            int ko = 32 * kk + 8 * quad;
            bf16x8 bf = *(const bf16x8*)&cur[l15][ko];
            #pragma unroll
            for (int g = 0; g < 4; ++g) {
                bf16x8 sa = *(const bf16x8*)(sbase[g] + 32 * kk);
                aR[g] = MFMA16(af[g][kk], bf, aR[g]);
                aS[g] = MFMA16(sa,        bf, aS[g]);
            }
        }

        // -- phase 2: cell update (regs) + write h_{t+1} to nxt --
        #pragma unroll
        for (int half = 0; half < 2; ++half) {
            float hh[4];
            #pragma unroll
            for (int r = 0; r < 4; ++r) {
                float iv = half ? aS[0][r] : aR[0][r];
                float fv = half ? aS[1][r] : aR[1][r];
                float gv = half ? aS[2][r] : aR[2][r];
                float ov = half ? aS[3][r] : aR[3][r];
                float cc = sigm(fv) * c[half][r] + sigm(iv) * tanh_f(gv);
                c[half][r] = cc;
                hh[r] = sigm(ov) * tanh_f(cc);
            }
            int dim = (half ? sd0 : rd0) + 4 * quad;
            *(unsigned*)&nxt[l15][dim]     = pk2(hh[0], hh[1]);
            *(unsigned*)&nxt[l15][dim + 2] = pk2(hh[2], hh[3]);
        }
        __syncthreads();   // B1: h_{t+1} complete

        // -- phase 3: z = relu(h_{t+1} @ Wo1^T + bo1); wave wv -> z-dims [16wv,16wv+16) --
        {
            f32x4 za = zero4;
            #pragma unroll
            for (int kk = 0; kk < 9; ++kk) {
                int ko = 32 * kk + 8 * quad;
                bf16x8 a = *(const bf16x8*)&wo1l[16 * wv + l15][ko];
                bf16x8 b = *(const bf16x8*)&nxt[l15][ko];   // stale x cols harmless: Wo1ext=0 there
                za = MFMA16(a, b, za);
            }
            int zd = 16 * wv + 4 * quad;
            *(unsigned*)&zbuf[l15][zd]     = pk2(fmaxf(za[0], 0.f), fmaxf(za[1], 0.f));
            *(unsigned*)&zbuf[l15][zd + 2] = pk2(fmaxf(za[2], 0.f), fmaxf(za[3], 0.f));
        }
        __syncthreads();   // B2: z complete

        // -- phase 4 (wave 0): y = z @ Wo2^T + bo2; emit out + x_{t+1} --
        if (wv == 0) {
            f32x4 ya = zero4;
            #pragma unroll
            for (int kk = 0; kk < 4; ++kk) {
                int ko = 32 * kk + 8 * quad;
                ya = MFMA16(*(const bf16x8*)&wo2l[l15][ko],
                            *(const bf16x8*)&zbuf[l15][ko], ya);
            }
            if (quad == 0) {
                float y0 = ya[0] + bo2[0], y1 = ya[1] + bo2[1], y2 = ya[2] + bo2[2];
                float* op = out + ((size_t)(gb + l15) * TSTEPS + t) * 3;
                op[0] = y0; op[1] = y1; op[2] = y2;
                *(unsigned*)&nxt[l15][256] = pk2(y0, y1);
                *(unsigned*)&nxt[l15][258] = pk2(y2, 1.f);  // keep ones col = 1
            }
        }
        __syncthreads();   // B3: x_{t+1} visible
    }
}

extern "C" void kernel_launch(void* const* d_in, const int* in_sizes, int n_in,
                              void* d_out, int out_size, void* d_ws, size_t ws_size,
                              hipStream_t stream)
{
    const float* meta = (const float*)d_in[0];
    const float* W1   = (const float*)d_in[2];
    const float* b1   = (const float*)d_in[3];
    const float* W2   = (const float*)d_in[4];
    const float* b2   = (const float*)d_in[5];
    const float* Wih  = (const float*)d_in[6];
    const float* Whh  = (const float*)d_in[7];
    const float* bih  = (const float*)d_in[8];
    const float* bhh  = (const float*)d_in[9];
    const float* Wo1  = (const float*)d_in[10];
    const float* bo1  = (const float*)d_in[11];
    const float* Wo2  = (const float*)d_in[12];
    const float* bo2  = (const float*)d_in[13];
    bf16_t* ws  = (bf16_t*)d_ws;
    float*  out = (float*)d_out;

    prep_kernel<<<dim3((WS_ELEMS + 255) / 256), dim3(256), 0, stream>>>(
        W2, b2, Wih, Whh, bih, bhh, Wo1, bo1, Wo2, ws);
    lstm_main<<<dim3(4096 / TILE_B), dim3(512), 0, stream>>>(
        meta, W1, b1, bo2, ws, out);
}

// Round 4
// 1403.412 us; speedup vs baseline: 15.1022x; 1.0629x over previous
//
#include <hip/hip_runtime.h>

typedef __bf16 bf16_t;
typedef bf16_t bf16x8 __attribute__((ext_vector_type(8)));
typedef float  f32x4  __attribute__((ext_vector_type(4)));

#define MFMA16(A, B, C) __builtin_amdgcn_mfma_f32_16x16x32_bf16((A), (B), (C), 0, 0, 0)

static constexpr int KEXT   = 288;  // 256 h | 3 x | 1 ones(bias) | 28 zero pad
static constexpr int HS     = 296;  // LDS row stride (592 B: 16B-aligned, 2-way bank alias only)
static constexpr int TSTEPS = 128;
static constexpr int TILE_B = 16;   // grid 256 -> 1 block/CU

// ws layout (bf16 elements)
static constexpr int WALL_OFF = 0;                    // [1152][288] gates(1024) + Wo1ext(128)
static constexpr int W2E_OFF  = 1152 * 288;           // [512][288]  encoder layer2 (+b2 col)
static constexpr int WO2E_OFF = W2E_OFF + 512 * 288;  // [16][128]   Wo2 padded
static constexpr int WS_ELEMS = WO2E_OFF + 16 * 128;

// ---------------- prep: pack weights bf16 (ws re-poisoned every launch) ----------------
__global__ __launch_bounds__(256) void prep_kernel(
    const float* __restrict__ W2,  const float* __restrict__ b2,
    const float* __restrict__ Wih, const float* __restrict__ Whh,
    const float* __restrict__ bih, const float* __restrict__ bhh,
    const float* __restrict__ Wo1, const float* __restrict__ bo1,
    const float* __restrict__ Wo2, bf16_t* __restrict__ ws)
{
    int idx = blockIdx.x * 256 + threadIdx.x;
    if (idx < 1152 * 288) {
        int r = idx / 288, k = idx - r * 288;
        float v = 0.f;
        if (r < 1024) {                       // gate rows: i f g o (256 each)
            if (k < 256)       v = Whh[r * 256 + k];
            else if (k < 259)  v = Wih[r * 3 + (k - 256)];
            else if (k == 259) v = bih[r] + bhh[r];
        } else {                              // Wo1 rows (zeros at x cols, bo1 at ones col)
            int q = r - 1024;
            if (k < 256)       v = Wo1[q * 256 + k];
            else if (k == 259) v = bo1[q];
        }
        ws[WALL_OFF + idx] = (bf16_t)v;
    } else if (idx < W2E_OFF + 512 * 288) {
        int j = idx - W2E_OFF;
        int u = j / 288, k = j - u * 288;
        float v = 0.f;
        if (k < 256)       v = W2[u * 256 + k];
        else if (k == 259) v = b2[u];
        ws[idx] = (bf16_t)v;
    } else if (idx < WS_ELEMS) {
        int j = idx - WO2E_OFF;
        int d = j >> 7, q = j & 127;
        ws[idx] = (bf16_t)((d < 3) ? Wo2[d * 128 + q] : 0.f);
    }
}

__device__ __forceinline__ float sigm(float x) { return 1.f / (1.f + __expf(-x)); }
__device__ __forceinline__ float tanh_f(float x) {
    float a = fminf(fmaxf(x, -15.f), 15.f);
    float e = __expf(2.f * a);
    return (e - 1.f) / (e + 1.f);
}
__device__ __forceinline__ unsigned pk2(float a, float b) {
    union { bf16_t h[2]; unsigned u; } x;
    x.h[0] = (bf16_t)a; x.h[1] = (bf16_t)b; return x.u;
}

// ---------------- main: 256 blocks x 512 thr; block owns 16 batches end-to-end.
// Wave wv owns dims [32wv,32wv+32) x 4 gates. Resident in VGPRs: gate 0 (i) only,
// af[2][9] = 72 VGPR. Gates 1..3 streamed from L2 with explicit 2-deep prefetch
// (6 frags = 24 VGPR in flight per buffer). Total est pressure ~214 < 256: NO SPILL.
__global__ __launch_bounds__(512, 2) void lstm_main(
    const float* __restrict__ meta, const float* __restrict__ W1,
    const float* __restrict__ b1,   const float* __restrict__ bo2,
    const bf16_t* __restrict__ ws,  float* __restrict__ out)
{
    __shared__ __align__(16) bf16_t hx[2][TILE_B][HS];  // [h(256)|x(3)|1|pad] double-buffered
    __shared__ __align__(16) bf16_t wo1l[128][HS];      // Wo1ext; aliased as cbuf fp32 in setup
    __shared__ __align__(16) bf16_t wo2l[16][136];
    __shared__ __align__(16) bf16_t zbuf[TILE_B][136];

    const int tid  = threadIdx.x;
    const int wv   = tid >> 6;       // 0..7
    const int lane = tid & 63;
    const int l15  = lane & 15;
    const int quad = lane >> 4;      // 0..3
    const int gb   = blockIdx.x * TILE_B;

    const bf16_t* wall = ws + WALL_OFF;
    const bf16_t* w2e  = ws + W2E_OFF;
    const bf16_t* wo2e = ws + WO2E_OFF;
    const f32x4 zero4 = {0.f, 0.f, 0.f, 0.f};

    // ---- init ext cols of both hx buffers (x0 in buf0; ones col; zero pad) ----
    if (tid < 32) {
        int buf = tid >> 4, b = tid & 15;
        for (int c = 256; c < HS; ++c) {
            float v = 0.f;
            if (c < 259)       v = buf ? 0.f : meta[(size_t)(gb + b) * 7 + (c - 256)];
            else if (c == 259) v = 1.f;
            hx[buf][b][c] = (bf16_t)v;
        }
    }
    // ---- enc1 (VALU, K=7) into hx[1] ----
    {
        int b = tid & 15, j0 = (tid >> 4) * 8;
        float m[7];
        #pragma unroll
        for (int k = 0; k < 7; ++k) m[k] = meta[(size_t)(gb + b) * 7 + k];
        #pragma unroll
        for (int jj = 0; jj < 8; ++jj) {
            int jd = j0 + jj;
            float acc = b1[jd];
            #pragma unroll
            for (int k = 0; k < 7; ++k) acc += W1[jd * 7 + k] * m[k];
            hx[1][b][jd] = (bf16_t)fmaxf(acc, 0.f);
        }
    }
    __syncthreads();

    // ---- enc2 via MFMA: wave wv rows [64wv,64wv+64); rows<256 -> h0(hx[0]), >=256 -> c0(cbuf) ----
    float* cbuf = (float*)&wo1l[0][0];  // fp32 [256][17]
    {
        f32x4 e[4] = {zero4, zero4, zero4, zero4};
        #pragma unroll
        for (int kk = 0; kk < 9; ++kk) {
            int ko = 32 * kk + 8 * quad;
            bf16x8 bf = *(const bf16x8*)&hx[1][l15][ko];
            #pragma unroll
            for (int m = 0; m < 4; ++m) {
                bf16x8 a = *(const bf16x8*)&w2e[(size_t)(64 * wv + 16 * m + l15) * KEXT + ko];
                e[m] = MFMA16(a, bf, e[m]);
            }
        }
        #pragma unroll
        for (int m = 0; m < 4; ++m) {
            int row = 64 * wv + 16 * m + 4 * quad;
            if (row < 256) {  // h0
                *(unsigned*)&hx[0][l15][row]     = pk2(fmaxf(e[m][0], 0.f), fmaxf(e[m][1], 0.f));
                *(unsigned*)&hx[0][l15][row + 2] = pk2(fmaxf(e[m][2], 0.f), fmaxf(e[m][3], 0.f));
            } else {          // c0
                int d = row - 256;
                #pragma unroll
                for (int r = 0; r < 4; ++r)
                    cbuf[(size_t)(d + r) * 17 + l15] = fmaxf(e[m][r], 0.f);
            }
        }
    }
    __syncthreads();

    // ---- c0 -> regs: c[half][r] at dim 32wv+16half+4quad+r, batch l15 ----
    f32x4 c[2];
    #pragma unroll
    for (int half = 0; half < 2; ++half)
        #pragma unroll
        for (int r = 0; r < 4; ++r)
            c[half][r] = cbuf[(size_t)(32 * wv + 16 * half + 4 * quad + r) * 17 + l15];
    __syncthreads();

    // ---- Wo1 -> LDS (overwrites cbuf); Wo2 -> LDS ----
    #pragma unroll
    for (int i = 0; i < 9; ++i) {
        int idx = tid + 512 * i;
        int r = idx / 36, c8 = idx - r * 36;
        *(bf16x8*)&wo1l[r][8 * c8] = *(const bf16x8*)&wall[(size_t)(1024 + r) * KEXT + 8 * c8];
    }
    #pragma unroll
    for (int i = 0; i < 4; ++i) {
        int idx = tid + 512 * i;
        int r = idx >> 7, cc = idx & 127;
        wo2l[r][cc] = wo2e[r * 128 + cc];
    }

    // ---- resident A-frags: gate 0 (i), dims [32wv,32wv+32): af[half][kk], 72 VGPR ----
    bf16x8 af[2][9];
    #pragma unroll
    for (int h = 0; h < 2; ++h)
        #pragma unroll
        for (int kk = 0; kk < 9; ++kk)
            af[h][kk] = *(const bf16x8*)&wall[(size_t)(32 * wv + 16 * h + l15) * KEXT + 32 * kk + 8 * quad];

    // streamed base: gates 1..3, offset (256g + 16h)*KEXT + 32kk from sb
    const bf16_t* sb = wall + (size_t)(32 * wv + l15) * KEXT + 8 * quad;

    __syncthreads();

    // ================= time loop =================
    for (int t = 0; t < TSTEPS; ++t) {
        const bf16_t (*cur)[HS] = hx[t & 1];
        bf16_t (*nxt)[HS]       = hx[(t + 1) & 1];

        // -- phase 1: gates = [h|x|1] @ Wall^T; gate0 from regs, gates1..3 streamed w/ prefetch --
        f32x4 acc[4][2];
        #pragma unroll
        for (int g = 0; g < 4; ++g) { acc[g][0] = zero4; acc[g][1] = zero4; }

        bf16x8 s0[6], s1[6];
        #pragma unroll
        for (int i = 0; i < 6; ++i) {
            int g = 1 + (i >> 1), h = i & 1;
            s0[i] = *(const bf16x8*)(sb + (size_t)(256 * g + 16 * h) * KEXT);
        }
        #pragma unroll
        for (int kk = 0; kk < 9; ++kk) {
            int ko = 32 * kk + 8 * quad;
            bf16x8 bf = *(const bf16x8*)&cur[l15][ko];
            if (kk < 8) {   // prefetch next k-slice into the other buffer
                #pragma unroll
                for (int i = 0; i < 6; ++i) {
                    int g = 1 + (i >> 1), h = i & 1;
                    bf16x8 v = *(const bf16x8*)(sb + (size_t)(256 * g + 16 * h) * KEXT + 32 * (kk + 1));
                    if (kk & 1) s0[i] = v; else s1[i] = v;
                }
            }
            acc[0][0] = MFMA16(af[0][kk], bf, acc[0][0]);
            acc[0][1] = MFMA16(af[1][kk], bf, acc[0][1]);
            #pragma unroll
            for (int i = 0; i < 6; ++i) {
                int g = 1 + (i >> 1), h = i & 1;
                bf16x8 a = (kk & 1) ? s1[i] : s0[i];
                acc[g][h] = MFMA16(a, bf, acc[g][h]);
            }
        }

        // -- phase 2: cell update (regs) + write h_{t+1} --
        #pragma unroll
        for (int half = 0; half < 2; ++half) {
            float hh[4];
            #pragma unroll
            for (int r = 0; r < 4; ++r) {
                float iv = acc[0][half][r], fv = acc[1][half][r];
                float gv = acc[2][half][r], ov = acc[3][half][r];
                float cc = sigm(fv) * c[half][r] + sigm(iv) * tanh_f(gv);
                c[half][r] = cc;
                hh[r] = sigm(ov) * tanh_f(cc);
            }
            int dim = 32 * wv + 16 * half + 4 * quad;
            *(unsigned*)&nxt[l15][dim]     = pk2(hh[0], hh[1]);
            *(unsigned*)&nxt[l15][dim + 2] = pk2(hh[2], hh[3]);
        }
        __syncthreads();   // B1: h_{t+1} complete

        // -- phase 3: z = relu(h_{t+1} @ Wo1^T + bo1); wave wv -> z-dims [16wv,16wv+16) --
        {
            f32x4 za = zero4;
            #pragma unroll
            for (int kk = 0; kk < 9; ++kk) {
                int ko = 32 * kk + 8 * quad;
                bf16x8 a = *(const bf16x8*)&wo1l[16 * wv + l15][ko];
                bf16x8 b = *(const bf16x8*)&nxt[l15][ko];   // stale x cols harmless: Wo1ext=0 there
                za = MFMA16(a, b, za);
            }
            int zd = 16 * wv + 4 * quad;
            *(unsigned*)&zbuf[l15][zd]     = pk2(fmaxf(za[0], 0.f), fmaxf(za[1], 0.f));
            *(unsigned*)&zbuf[l15][zd + 2] = pk2(fmaxf(za[2], 0.f), fmaxf(za[3], 0.f));
        }
        __syncthreads();   // B2: z complete

        // -- phase 4 (wave 0): y = z @ Wo2^T + bo2; emit out + x_{t+1} --
        if (wv == 0) {
            f32x4 ya = zero4;
            #pragma unroll
            for (int kk = 0; kk < 4; ++kk) {
                int ko = 32 * kk + 8 * quad;
                ya = MFMA16(*(const bf16x8*)&wo2l[l15][ko],
                            *(const bf16x8*)&zbuf[l15][ko], ya);
            }
            if (quad == 0) {
                float y0 = ya[0] + bo2[0], y1 = ya[1] + bo2[1], y2 = ya[2] + bo2[2];
                float* op = out + ((size_t)(gb + l15) * TSTEPS + t) * 3;
                op[0] = y0; op[1] = y1; op[2] = y2;
                *(unsigned*)&nxt[l15][256] = pk2(y0, y1);
                *(unsigned*)&nxt[l15][258] = pk2(y2, 1.f);  // keep ones col = 1
            }
        }
        __syncthreads();   // B3: x_{t+1} visible
    }
}

extern "C" void kernel_launch(void* const* d_in, const int* in_sizes, int n_in,
                              void* d_out, int out_size, void* d_ws, size_t ws_size,
                              hipStream_t stream)
{
    const float* meta = (const float*)d_in[0];
    const float* W1   = (const float*)d_in[2];
    const float* b1   = (const float*)d_in[3];
    const float* W2   = (const float*)d_in[4];
    const float* b2   = (const float*)d_in[5];
    const float* Wih  = (const float*)d_in[6];
    const float* Whh  = (const float*)d_in[7];
    const float* bih  = (const float*)d_in[8];
    const float* bhh  = (const float*)d_in[9];
    const float* Wo1  = (const float*)d_in[10];
    const float* bo1  = (const float*)d_in[11];
    const float* Wo2  = (const float*)d_in[12];
    const float* bo2  = (const float*)d_in[13];
    bf16_t* ws  = (bf16_t*)d_ws;
    float*  out = (float*)d_out;

    prep_kernel<<<dim3((WS_ELEMS + 255) / 256), dim3(256), 0, stream>>>(
        W2, b2, Wih, Whh, bih, bhh, Wo1, bo1, Wo2, ws);
    lstm_main<<<dim3(4096 / TILE_B), dim3(512), 0, stream>>>(
        meta, W1, b1, bo2, ws, out);
}